// Round 2
// baseline (6438.289 us; speedup 1.0000x reference)
//
#include <hip/hip_runtime.h>
#include <hip/hip_bf16.h>
#include <math.h>

// Problem constants
#define B_  32
#define C_  256
#define H_  64
#define W_  64
#define K_  17
#define HW_ 4096

// Output layout (flat concat of heat, off, var, fw, coords, scores)
#define HEAT_OFF  0
#define OFF_OFF   2228224          // 32*17*64*64
#define VAR_OFF   6684672          // + 32*17*2*64*64
#define FW_OFF    8912896          // + 32*17*64*64
#define COORD_OFF 8912897
#define SCORE_OFF 8913985

// g / sqrt(1 + 1e-5)
#define BN_SCALE 0.9999950000374997f

typedef __attribute__((ext_vector_type(8))) short  bf16x8;
typedef __attribute__((ext_vector_type(4))) float  f32x4;

__device__ __forceinline__ unsigned short f2bf(float x) {
  unsigned int u = __float_as_uint(x);
  u = u + 0x7fffu + ((u >> 16) & 1u);
  return (unsigned short)(u >> 16);
}
__device__ __forceinline__ float bf2f(unsigned short h) {
  return __uint_as_float(((unsigned int)h) << 16);
}

// ---------------------------------------------------------------------------
// Workspace layout (bytes)
// ---------------------------------------------------------------------------
#define SZP_ELEMS  35684352ull                    // 32*66*66*256 (one packed tensor)
#define SZP_BYTES  71368704ull
#define XP_HI   0ull
#define XP_LO   71368704ull
#define S1_HI   142737408ull
#define S1_LO   214106112ull
#define S2_HI   285474816ull
#define S2_LO   356843520ull
#define WP_BASE 428212224ull
// per 256-co conv: hi 1179648 B + lo 1179648 B
#define WS1_HI  (WP_BASE)
#define WS1_LO  (WP_BASE + 1179648ull)
#define WS2_HI  (WP_BASE + 2359296ull)
#define WS2_LO  (WP_BASE + 3538944ull)
#define WH1_HI  (WP_BASE + 4718592ull)
#define WH1_LO  (WP_BASE + 5898240ull)
#define WO1_HI  (WP_BASE + 7077888ull)
#define WO1_LO  (WP_BASE + 8257536ull)
#define WV1_HI  (WP_BASE + 9437184ull)
#define WV1_LO  (WP_BASE + 10027008ull)
#define CG_OFF  (WP_BASE + 10616832ull)

// ---------------------------------------------------------------------------
// pack_x: fp32 NCHW -> zero-padded NHWC bf16 hi/lo [32][66][66][256]
// ---------------------------------------------------------------------------
__global__ __launch_bounds__(256) void pack_x(
    const float* __restrict__ x, unsigned short* __restrict__ hi,
    unsigned short* __restrict__ lo) {
  __shared__ float s[128 * 66];
  const int b  = blockIdx.x / 66;
  const int pr = blockIdx.x % 66;
  const size_t obase = ((size_t)(b * 66 + pr) * 66) * 256;
  if (pr == 0 || pr == 65) {
    for (int i = threadIdx.x; i < 66 * 256; i += 256) { hi[obase + i] = 0; lo[obase + i] = 0; }
    return;
  }
  const int y = pr - 1;
  for (int h = 0; h < 2; ++h) {
    __syncthreads();
    for (int i = threadIdx.x; i < 128 * 66; i += 256) {
      int c = i / 66, pc = i % 66;
      int xx = pc - 1;
      float v = (xx >= 0 && xx < 64)
          ? x[((size_t)b * 256 + h * 128 + c) * 4096 + y * 64 + xx] : 0.f;
      s[i] = v;
    }
    __syncthreads();
    for (int i = threadIdx.x; i < 66 * 128; i += 256) {
      int pc = i / 128, c = i % 128;
      float v = s[c * 66 + pc];
      unsigned short hb = f2bf(v);
      size_t o = obase + (size_t)pc * 256 + h * 128 + c;
      hi[o] = hb;
      lo[o] = f2bf(v - bf2f(hb));
    }
  }
}

// ---------------------------------------------------------------------------
// pack_w: OIHW fp32 -> [tap][co][ci] bf16 hi/lo
// ---------------------------------------------------------------------------
__global__ void pack_w(const float* __restrict__ w, unsigned short* __restrict__ hi,
                       unsigned short* __restrict__ lo, int COUT) {
  int i = blockIdx.x * 256 + threadIdx.x;
  int tot = COUT * 256 * 9;
  if (i >= tot) return;
  int co = i / (256 * 9);
  int r  = i - co * 256 * 9;
  int ci = r / 9;
  int k  = r - ci * 9;
  float v = w[i];
  unsigned short h = f2bf(v);
  size_t o = ((size_t)k * COUT + co) * 256 + ci;
  hi[o] = h;
  lo[o] = f2bf(v - bf2f(h));
}

// ---------------------------------------------------------------------------
// zero_border: zero the halo of a packed activation tensor pair
// ---------------------------------------------------------------------------
__global__ void zero_border(unsigned short* __restrict__ hi, unsigned short* __restrict__ lo) {
  int i = blockIdx.x * 256 + threadIdx.x;   // 32 * 260 * 256
  if (i >= 32 * 260 * 256) return;
  int c = i & 255;
  int p = i >> 8;
  int b = p / 260;
  int q = p - b * 260;
  int pr, pc;
  if (q < 66) { pr = 0; pc = q; }
  else if (q < 132) { pr = 65; pc = q - 66; }
  else { int u = q - 132; pr = 1 + (u >> 1); pc = (u & 1) * 65; }
  size_t o = ((size_t)(b * 66 + pr) * 66 + pc) * 256 + c;
  hi[o] = 0; lo[o] = 0;
}

// ---------------------------------------------------------------------------
// MFMA 3x3 conv + BN + ReLU.  Split-bf16 3-pass (hi*hi + lo*hi + hi*lo).
// Block: 128 px (2 rows x 64) x 128 cout.  256 threads = 4 waves.
//   - A tile (264 px x 32ci, hi/lo) in LDS, single buffer per chunk,
//     XOR-swizzled: cell(p, hl, q) at p*128 + ((hl*4|q)^(p&7))*16.
//     Staging writes are LINEAR (idx*16) -> conflict-free; reads 2-way (free).
//   - B tile (128 co x 32ci, hi/lo) in LDS, same swizzle (co in place of p),
//     register-staged one slot ahead (bpref, 16 VGPR -- no spills).
//   - Per-slot tail: barrier; writeB(+writeI); barrier; loadB(s+2) -- the
//     vmcnt(0) drain at a barrier only ever covers loads issued a full
//     48-MFMA section earlier.
//   - Epilogue transposes acc through LDS -> fully coalesced uint4 stores.
//   - XCD-chunked block swizzle for L2 reuse of the input tile.
// ---------------------------------------------------------------------------
#define ABUF_BYTES 33792           // 264 px * 128 B
#define BOFF_BYTES 33792
#define BBUF_BYTES 16384           // 128 co * 128 B
#define SMEM_SZ    50176

template <int COUT, int OUTMODE>
__global__ __launch_bounds__(256, 2) void conv3x3_mfma(
    const unsigned short* __restrict__ Phi, const unsigned short* __restrict__ Plo,
    const unsigned short* __restrict__ Whi, const unsigned short* __restrict__ Wlo,
    const float* __restrict__ gam, const float* __restrict__ bet,
    unsigned short* __restrict__ Ohi, unsigned short* __restrict__ Olo,
    float* __restrict__ Ofp) {
  // ---- XCD-chunked swizzle: 8 XCDs, contiguous logical range per XCD ----
  constexpr int NWG = (COUT == 256) ? 2048 : 1024;
  constexpr int PER = NWG >> 3;
  const int L = (blockIdx.x & 7) * PER + (blockIdx.x >> 3);
  int mb, nblk;
  if (COUT == 256) { nblk = L & 1; mb = L >> 1; }
  else             { nblk = 0;     mb = L; }

  const int b     = mb >> 5;
  const int ypair = mb & 31;
  const int Y     = ypair * 2;          // padded input row base (= first out y)

  const int tid  = threadIdx.x;
  const int lane = tid & 63;
  const int wv   = tid >> 6;
  const int l15  = lane & 15;
  const int quad = lane >> 4;
  const int mhalf = (wv & 1) * 64;
  const int nbase = (wv >> 1) * 64;

  __shared__ __align__(16) char smem[SMEM_SZ];

  // per-mi pixel index base (p = pb + tap offset)
  int pb[4];
#pragma unroll
  for (int mi = 0; mi < 4; ++mi) {
    int px = mhalf + mi * 16 + l15;
    pb[mi] = (px >> 6) * 66 + (px & 63);
  }
  // B read offsets (fixed per thread)
  int boffs[4];
#pragma unroll
  for (int ni = 0; ni < 4; ++ni) {
    int col = nbase + ni * 16 + l15;                 // 0..127
    boffs[ni] = BOFF_BYTES + (col << 7) + (((quad ^ col) & 7) << 4);
  }

  f32x4 acc[4][4];
#pragma unroll
  for (int mi = 0; mi < 4; ++mi)
#pragma unroll
    for (int ni = 0; ni < 4; ++ni) acc[mi][ni] = (f32x4)0.f;

  const size_t ibase = ((size_t)(b * 66 + Y) * 66) * 256;  // shorts

  uint4 ipref[9];
  uint4 bpref[4];

  // ---- staging helpers ----
  auto loadB = [&](int tt, int cc) {
#pragma unroll
    for (int j = 0; j < 4; ++j) {
      int idx = tid + j * 256;
      int co = idx >> 3, s = idx & 7;
      int hq = s ^ (co & 7);
      const unsigned short* src = (hq & 4) ? Wlo : Whi;
      bpref[j] = *(const uint4*)(src + (size_t)tt * (COUT * 256)
                                 + ((size_t)(nblk * 128 + co)) * 256 + cc * 32 + (hq & 3) * 8);
    }
  };
  auto writeB = [&]() {
#pragma unroll
    for (int j = 0; j < 4; ++j) {
      int idx = tid + j * 256;
      *(uint4*)(smem + BOFF_BYTES + idx * 16) = bpref[j];
    }
  };
  auto loadI = [&](int cc) {
#pragma unroll
    for (int j = 0; j < 9; ++j) {
      int idx = tid + j * 256;
      if (idx < 2112) {
        int p = idx >> 3, s = idx & 7;
        int hq = s ^ (p & 7);                       // hl*4 | q
        const unsigned short* src = (hq & 4) ? Plo : Phi;
        ipref[j] = *(const uint4*)(src + ibase + (size_t)p * 256 + (hq & 3) * 8 + cc * 32);
      }
    }
  };
  auto writeI = [&]() {
#pragma unroll
    for (int j = 0; j < 9; ++j) {
      int idx = tid + j * 256;
      if (idx < 2112)
        *(uint4*)(smem + idx * 16) = ipref[j];
    }
  };

  // ---- prologue: stage A chunk 0 and B slot 0; prefetch B slot 1 ----
  loadI(0);
  loadB(0, 0);
  writeI();
  writeB();
  __syncthreads();
  loadB(1, 0);                       // bpref = B[slot 1]

  // ---- main loop: 8 chunks x 9 taps ----
  for (int c = 0; c < 8; ++c) {
#pragma unroll
    for (int t = 0; t < 9; ++t) {
      if (t == 8 && c < 7) loadI(c + 1);           // issue next-chunk HBM loads
      const int dtap = (t / 3) * 66 + (t % 3);
      bf16x8 ah[4], al[4], bh[4], bl[4];
#pragma unroll
      for (int mi = 0; mi < 4; ++mi) {
        int p = pb[mi] + dtap;
        int a = (p << 7) + (((quad ^ p) & 7) << 4);
        ah[mi] = *(const bf16x8*)(smem + a);
        al[mi] = *(const bf16x8*)(smem + (a ^ 64));
      }
#pragma unroll
      for (int ni = 0; ni < 4; ++ni) {
        bh[ni] = *(const bf16x8*)(smem + boffs[ni]);
        bl[ni] = *(const bf16x8*)(smem + (boffs[ni] ^ 64));
      }
#pragma unroll
      for (int mi = 0; mi < 4; ++mi)
#pragma unroll
        for (int ni = 0; ni < 4; ++ni) {
          acc[mi][ni] = __builtin_amdgcn_mfma_f32_16x16x32_bf16(ah[mi], bh[ni], acc[mi][ni], 0, 0, 0);
          acc[mi][ni] = __builtin_amdgcn_mfma_f32_16x16x32_bf16(al[mi], bh[ni], acc[mi][ni], 0, 0, 0);
          acc[mi][ni] = __builtin_amdgcn_mfma_f32_16x16x32_bf16(ah[mi], bl[ni], acc[mi][ni], 0, 0, 0);
        }

      if (!(c == 7 && t == 8)) {
        __syncthreads();              // all reads of B[s] (and A[c] at t==8) done
        writeB();                     // LDS <- B[s+1]
        if (t == 8) writeI();         // LDS <- A chunk c+1
        __syncthreads();
        int nt = (t <= 6) ? t + 2 : t - 7;
        int nc = (t <= 6) ? c : c + 1;
        if (nc > 7) { nc = 7; nt = 8; }   // harmless tail reload
        loadB(nt, nc);                // bpref <- B[s+2]; drains at NEXT barrier
      }
    }
  }

  // ---- epilogue: BN + ReLU, transpose through LDS, coalesced stores ----
  float scn[4], bin[4];
#pragma unroll
  for (int ni = 0; ni < 4; ++ni) {
    int co = nblk * 128 + nbase + ni * 16 + l15;
    scn[ni] = gam[co] * BN_SCALE;
    bin[ni] = bet[co];
  }

  float* SL = (float*)smem;                         // [64][129] f32 per pass
#pragma unroll
  for (int pass = 0; pass < 2; ++pass) {
    if ((wv & 1) == pass) {
#pragma unroll
      for (int mi = 0; mi < 4; ++mi)
#pragma unroll
        for (int ni = 0; ni < 4; ++ni)
#pragma unroll
          for (int r = 0; r < 4; ++r) {
            int lpx = mi * 16 + quad * 4 + r;       // 0..63 within this pass
            int co  = nbase + ni * 16 + l15;        // 0..127
            SL[lpx * 129 + co] = fmaxf(acc[mi][ni][r] * scn[ni] + bin[ni], 0.f);
          }
    }
    __syncthreads();
    if (OUTMODE == 0) {
#pragma unroll
      for (int it = 0; it < 4; ++it) {
        int u = it * 256 + tid;
        int lpx = u >> 4, oct = u & 15;
        const float* row = SL + lpx * 129 + oct * 8;
        __align__(16) unsigned short hs[8], ls[8];
#pragma unroll
        for (int j = 0; j < 8; ++j) {
          float v = row[j];
          unsigned short hb = f2bf(v);
          hs[j] = hb;
          ls[j] = f2bf(v - bf2f(hb));
        }
        size_t o = ((size_t)(b * 66 + Y + pass + 1) * 66 + lpx + 1) * 256 + nblk * 128 + oct * 8;
        *(uint4*)(Ohi + o) = *(const uint4*)hs;
        *(uint4*)(Olo + o) = *(const uint4*)ls;
      }
    } else {
#pragma unroll
      for (int it = 0; it < 4; ++it) {
        int u = it * 256 + tid;
        int coL = u >> 3, xo = u & 7;
        __align__(16) float vv[8];
#pragma unroll
        for (int j = 0; j < 8; ++j) vv[j] = SL[(xo * 8 + j) * 129 + coL];
        size_t o = ((size_t)(b * COUT + nblk * 128 + coL)) * 4096 + (size_t)(Y + pass) * 64 + xo * 8;
        *(uint4*)(Ofp + o)     = *(const uint4*)&vv[0];
        *(uint4*)(Ofp + o + 4) = *(const uint4*)&vv[4];
      }
    }
    __syncthreads();
  }
}

// ---------------------------------------------------------------------------
// 1x1 conv + bias (+ optional softplus). One thread per pixel, CO accs.
// ---------------------------------------------------------------------------
template <int CO, int CIN>
__global__ __launch_bounds__(256) void conv1x1_kernel(
    const float* __restrict__ in, const float* __restrict__ w,
    const float* __restrict__ bias, float* __restrict__ out, int do_softplus) {
  __shared__ float s_w[CO * CIN];
  const int b   = blockIdx.x >> 4;
  const int pix = ((blockIdx.x & 15) << 8) + threadIdx.x;
  for (int i = threadIdx.x; i < CO * CIN; i += 256) s_w[i] = w[i];
  __syncthreads();

  float acc[CO];
#pragma unroll
  for (int co = 0; co < CO; ++co) acc[co] = 0.f;

  const float* ip = in + (size_t)b * CIN * HW_ + pix;
  for (int ci = 0; ci < CIN; ++ci) {
    float v = ip[(size_t)ci * HW_];
#pragma unroll
    for (int co = 0; co < CO; ++co) acc[co] = fmaf(v, s_w[co * CIN + ci], acc[co]);
  }
  float* op = out + (size_t)b * CO * HW_ + pix;
#pragma unroll
  for (int co = 0; co < CO; ++co) {
    float x = acc[co] + bias[co];
    if (do_softplus) x = fmaxf(x, 0.f) + log1pf(expf(-fabsf(x)));
    op[(size_t)co * HW_] = x;
  }
}

// ---------------------------------------------------------------------------
// soft-argmax over each (b,k) 64x64 heatmap
// ---------------------------------------------------------------------------
__global__ __launch_bounds__(256) void soft_argmax_kernel(
    const float* __restrict__ heat, float* __restrict__ cg,
    float* __restrict__ scores) {
  const int bk = blockIdx.x;
  const float* h = heat + (size_t)bk * HW_;
  const int tid = threadIdx.x;
  __shared__ float sred[256];

  float v[16];
  float lmax = -INFINITY;
#pragma unroll
  for (int i = 0; i < 16; ++i) {
    v[i] = h[tid + (i << 8)];
    lmax = fmaxf(lmax, v[i]);
  }
  sred[tid] = lmax; __syncthreads();
  for (int s = 128; s > 0; s >>= 1) {
    if (tid < s) sred[tid] = fmaxf(sred[tid], sred[tid + s]);
    __syncthreads();
  }
  const float m = sred[0];
  __syncthreads();

  float s = 0.f, sx = 0.f, sy = 0.f;
#pragma unroll
  for (int i = 0; i < 16; ++i) {
    int idx = tid + (i << 8);
    float e = expf(v[i] - m);
    s += e;
    sx += e * (float)(idx & 63);
    sy += e * (float)(idx >> 6);
  }
  sred[tid] = s; __syncthreads();
  for (int st = 128; st > 0; st >>= 1) { if (tid < st) sred[tid] += sred[tid + st]; __syncthreads(); }
  const float S = sred[0]; __syncthreads();
  sred[tid] = sx; __syncthreads();
  for (int st = 128; st > 0; st >>= 1) { if (tid < st) sred[tid] += sred[tid + st]; __syncthreads(); }
  const float SX = sred[0]; __syncthreads();
  sred[tid] = sy; __syncthreads();
  for (int st = 128; st > 0; st >>= 1) { if (tid < st) sred[tid] += sred[tid + st]; __syncthreads(); }
  const float SY = sred[0];

  if (tid == 0) {
    cg[bk * 2]     = SX / S;
    cg[bk * 2 + 1] = SY / S;
    scores[bk]     = m;
  }
}

// ---------------------------------------------------------------------------
// local refine + blend + bilinear offset sampling + final coords; writes fw.
// ---------------------------------------------------------------------------
__global__ void refine_kernel(
    const float* __restrict__ heat, const float* __restrict__ off,
    const float* __restrict__ cg, const float* __restrict__ alpha_p,
    const float* __restrict__ fusion_p, float* __restrict__ coords_out,
    float* __restrict__ fw_out) {
  const int kp = blockIdx.x * 64 + threadIdx.x;
  const float fw = 1.f / (1.f + expf(-fusion_p[0]));
  if (kp == 0) fw_out[0] = fw;
  if (kp >= B_ * K_) return;

  const float a = 1.f / (1.f + expf(-alpha_p[0]));
  const float* h = heat + (size_t)kp * HW_;
  const float cgx = cg[kp * 2];
  const float cgy = cg[kp * 2 + 1];
  const int px = (int)rintf(fminf(fmaxf(cgx, 0.f), 63.f));
  const int py = (int)rintf(fminf(fmaxf(cgy, 0.f), 63.f));

  float vals[25];
  float m = -INFINITY;
#pragma unroll
  for (int dy = 0; dy < 5; ++dy) {
    int ya = py + dy - 2;
    int yc = min(max(ya, 0), 63);
#pragma unroll
    for (int dx = 0; dx < 5; ++dx) {
      int xa = px + dx - 2;
      int xc = min(max(xa, 0), 63);
      bool inb = (ya >= 0) && (ya < H_) && (xa >= 0) && (xa < W_);
      float val = inb ? h[yc * W_ + xc] : -INFINITY;
      vals[dy * 5 + dx] = val;
      m = fmaxf(m, val);
    }
  }
  float s = 0.f, rx = 0.f, ry = 0.f;
#pragma unroll
  for (int dy = 0; dy < 5; ++dy) {
    int ya = py + dy - 2;
    int yc = min(max(ya, 0), 63);
#pragma unroll
    for (int dx = 0; dx < 5; ++dx) {
      int xa = px + dx - 2;
      int xc = min(max(xa, 0), 63);
      float e = expf(vals[dy * 5 + dx] - m);
      s += e;
      rx += e * (float)xc;
      ry += e * (float)yc;
    }
  }
  rx /= s; ry /= s;

  float cx = a * cgx + (1.f - a) * rx;
  float cy = a * cgy + (1.f - a) * ry;

  const float ix = fminf(fmaxf(cx, 0.f), 63.f);
  const float iy = fminf(fmaxf(cy, 0.f), 63.f);
  const float x0 = floorf(ix), y0 = floorf(iy);
  const float wx = ix - x0, wy = iy - y0;
  const int x0i = min(max((int)x0, 0), 63);
  const int x1i = min(x0i + 1, 63);
  const int y0i = min(max((int)y0, 0), 63);
  const int y1i = min(y0i + 1, 63);

  float smp[2];
#pragma unroll
  for (int ch = 0; ch < 2; ++ch) {
    const float* oc = off + ((size_t)kp * 2 + ch) * HW_;
    float v00 = oc[y0i * W_ + x0i];
    float v01 = oc[y0i * W_ + x1i];
    float v10 = oc[y1i * W_ + x0i];
    float v11 = oc[y1i * W_ + x1i];
    smp[ch] = (1.f - wy) * ((1.f - wx) * v00 + wx * v01)
            + wy * ((1.f - wx) * v10 + wx * v11);
  }
  cx += fw * smp[0];
  cy += fw * smp[1];
  coords_out[kp * 2]     = cx;
  coords_out[kp * 2 + 1] = cy;
}

// ---------------------------------------------------------------------------
extern "C" void kernel_launch(void* const* d_in, const int* in_sizes, int n_in,
                              void* d_out, int out_size, void* d_ws, size_t ws_size,
                              hipStream_t stream) {
  const float* x    = (const float*)d_in[0];
  const float* w_s1 = (const float*)d_in[1];
  const float* g_s1 = (const float*)d_in[2];
  const float* b_s1 = (const float*)d_in[3];
  const float* w_s2 = (const float*)d_in[4];
  const float* g_s2 = (const float*)d_in[5];
  const float* b_s2 = (const float*)d_in[6];
  const float* w_h1 = (const float*)d_in[7];
  const float* g_h1 = (const float*)d_in[8];
  const float* b_h1 = (const float*)d_in[9];
  const float* w_h2 = (const float*)d_in[10];
  const float* c_h2 = (const float*)d_in[11];
  const float* w_o1 = (const float*)d_in[12];
  const float* g_o1 = (const float*)d_in[13];
  const float* b_o1 = (const float*)d_in[14];
  const float* w_o2 = (const float*)d_in[15];
  const float* c_o2 = (const float*)d_in[16];
  const float* w_v1 = (const float*)d_in[17];
  const float* g_v1 = (const float*)d_in[18];
  const float* b_v1 = (const float*)d_in[19];
  const float* w_v2 = (const float*)d_in[20];
  const float* c_v2 = (const float*)d_in[21];
  const float* alpha  = (const float*)d_in[22];
  const float* fusion = (const float*)d_in[23];

  float* out = (float*)d_out;
  char*  ws  = (char*)d_ws;

  unsigned short* xp_hi = (unsigned short*)(ws + XP_HI);
  unsigned short* xp_lo = (unsigned short*)(ws + XP_LO);
  unsigned short* s1_hi = (unsigned short*)(ws + S1_HI);
  unsigned short* s1_lo = (unsigned short*)(ws + S1_LO);
  unsigned short* s2_hi = (unsigned short*)(ws + S2_HI);
  unsigned short* s2_lo = (unsigned short*)(ws + S2_LO);
  unsigned short* ws1_hi = (unsigned short*)(ws + WS1_HI);
  unsigned short* ws1_lo = (unsigned short*)(ws + WS1_LO);
  unsigned short* ws2_hi = (unsigned short*)(ws + WS2_HI);
  unsigned short* ws2_lo = (unsigned short*)(ws + WS2_LO);
  unsigned short* wh1_hi = (unsigned short*)(ws + WH1_HI);
  unsigned short* wh1_lo = (unsigned short*)(ws + WH1_LO);
  unsigned short* wo1_hi = (unsigned short*)(ws + WO1_HI);
  unsigned short* wo1_lo = (unsigned short*)(ws + WO1_LO);
  unsigned short* wv1_hi = (unsigned short*)(ws + WV1_HI);
  unsigned short* wv1_lo = (unsigned short*)(ws + WV1_LO);
  float* F0  = (float*)(ws + 0);             // reuses XP region for h1/o1/v1 fp32
  float* cgb = (float*)(ws + CG_OFF);

  dim3 blk(256);

  // ---- pack inputs & weights, zero halos ----
  pack_x<<<32 * 66, blk, 0, stream>>>(x, xp_hi, xp_lo);
  pack_w<<<256 * 9, blk, 0, stream>>>(w_s1, ws1_hi, ws1_lo, 256);
  pack_w<<<256 * 9, blk, 0, stream>>>(w_s2, ws2_hi, ws2_lo, 256);
  pack_w<<<256 * 9, blk, 0, stream>>>(w_h1, wh1_hi, wh1_lo, 256);
  pack_w<<<256 * 9, blk, 0, stream>>>(w_o1, wo1_hi, wo1_lo, 256);
  pack_w<<<128 * 9, blk, 0, stream>>>(w_v1, wv1_hi, wv1_lo, 128);
  zero_border<<<8320, blk, 0, stream>>>(s1_hi, s1_lo);
  zero_border<<<8320, blk, 0, stream>>>(s2_hi, s2_lo);

  // ---- backbone convs (MFMA) ----
  conv3x3_mfma<256, 0><<<2048, blk, 0, stream>>>(xp_hi, xp_lo, ws1_hi, ws1_lo,
                                                 g_s1, b_s1, s1_hi, s1_lo, nullptr);
  conv3x3_mfma<256, 0><<<2048, blk, 0, stream>>>(s1_hi, s1_lo, ws2_hi, ws2_lo,
                                                 g_s2, b_s2, s2_hi, s2_lo, nullptr);
  conv3x3_mfma<256, 1><<<2048, blk, 0, stream>>>(s2_hi, s2_lo, wh1_hi, wh1_lo,
                                                 g_h1, b_h1, nullptr, nullptr, F0);
  conv1x1_kernel<17, 256><<<512, blk, 0, stream>>>(F0, w_h2, c_h2, out + HEAT_OFF, 0);
  conv3x3_mfma<256, 1><<<2048, blk, 0, stream>>>(s2_hi, s2_lo, wo1_hi, wo1_lo,
                                                 g_o1, b_o1, nullptr, nullptr, F0);
  conv1x1_kernel<34, 256><<<512, blk, 0, stream>>>(F0, w_o2, c_o2, out + OFF_OFF, 0);
  conv3x3_mfma<128, 1><<<1024, blk, 0, stream>>>(s2_hi, s2_lo, wv1_hi, wv1_lo,
                                                 g_v1, b_v1, nullptr, nullptr, F0);
  conv1x1_kernel<17, 128><<<512, blk, 0, stream>>>(F0, w_v2, c_v2, out + VAR_OFF, 1);

  // ---- heads ----
  soft_argmax_kernel<<<544, blk, 0, stream>>>(out + HEAT_OFF, cgb, out + SCORE_OFF);
  refine_kernel<<<9, dim3(64), 0, stream>>>(out + HEAT_OFF, out + OFF_OFF, cgb,
                                            alpha, fusion,
                                            out + COORD_OFF, out + FW_OFF);
}

// Round 3
// 2098.029 us; speedup vs baseline: 3.0687x; 3.0687x over previous
//
#include <hip/hip_runtime.h>
#include <hip/hip_bf16.h>
#include <math.h>

// Problem constants
#define B_  32
#define C_  256
#define H_  64
#define W_  64
#define K_  17
#define HW_ 4096

// Output layout (flat concat of heat, off, var, fw, coords, scores)
#define HEAT_OFF  0
#define OFF_OFF   2228224          // 32*17*64*64
#define VAR_OFF   6684672          // + 32*17*2*64*64
#define FW_OFF    8912896          // + 32*17*64*64
#define COORD_OFF 8912897
#define SCORE_OFF 8913985

// g / sqrt(1 + 1e-5)
#define BN_SCALE 0.9999950000374997f

typedef __attribute__((ext_vector_type(8))) short  bf16x8;
typedef __attribute__((ext_vector_type(4))) float  f32x4;

__device__ __forceinline__ unsigned short f2bf(float x) {
  unsigned int u = __float_as_uint(x);
  u = u + 0x7fffu + ((u >> 16) & 1u);
  return (unsigned short)(u >> 16);
}
__device__ __forceinline__ float bf2f(unsigned short h) {
  return __uint_as_float(((unsigned int)h) << 16);
}

// async global -> LDS, 16 B per lane.  lds must be wave-uniform base; the HW
// writes base + lane*16 (linear in lane order).
__device__ __forceinline__ void gload16(const void* g, void* l) {
  __builtin_amdgcn_global_load_lds(
      (const __attribute__((address_space(1))) void*)g,
      (__attribute__((address_space(3))) void*)l, 16, 0, 0);
}

// ---------------------------------------------------------------------------
// Workspace layout (bytes)
// ---------------------------------------------------------------------------
#define SZP_ELEMS  35684352ull                    // 32*66*66*256 (one packed tensor)
#define SZP_BYTES  71368704ull
#define XP_HI   0ull
#define XP_LO   71368704ull
#define S1_HI   142737408ull
#define S1_LO   214106112ull
#define S2_HI   285474816ull
#define S2_LO   356843520ull
#define WP_BASE 428212224ull
// per 256-co conv: hi 1179648 B + lo 1179648 B
#define WS1_HI  (WP_BASE)
#define WS1_LO  (WP_BASE + 1179648ull)
#define WS2_HI  (WP_BASE + 2359296ull)
#define WS2_LO  (WP_BASE + 3538944ull)
#define WH1_HI  (WP_BASE + 4718592ull)
#define WH1_LO  (WP_BASE + 5898240ull)
#define WO1_HI  (WP_BASE + 7077888ull)
#define WO1_LO  (WP_BASE + 8257536ull)
#define WV1_HI  (WP_BASE + 9437184ull)
#define WV1_LO  (WP_BASE + 10027008ull)
#define CG_OFF  (WP_BASE + 10616832ull)

// ---------------------------------------------------------------------------
// pack_x: fp32 NCHW -> zero-padded NHWC bf16 hi/lo [32][66][66][256]
// ---------------------------------------------------------------------------
__global__ __launch_bounds__(256) void pack_x(
    const float* __restrict__ x, unsigned short* __restrict__ hi,
    unsigned short* __restrict__ lo) {
  __shared__ float s[128 * 66];
  const int b  = blockIdx.x / 66;
  const int pr = blockIdx.x % 66;
  const size_t obase = ((size_t)(b * 66 + pr) * 66) * 256;
  if (pr == 0 || pr == 65) {
    for (int i = threadIdx.x; i < 66 * 256; i += 256) { hi[obase + i] = 0; lo[obase + i] = 0; }
    return;
  }
  const int y = pr - 1;
  for (int h = 0; h < 2; ++h) {
    __syncthreads();
    for (int i = threadIdx.x; i < 128 * 66; i += 256) {
      int c = i / 66, pc = i % 66;
      int xx = pc - 1;
      float v = (xx >= 0 && xx < 64)
          ? x[((size_t)b * 256 + h * 128 + c) * 4096 + y * 64 + xx] : 0.f;
      s[i] = v;
    }
    __syncthreads();
    for (int i = threadIdx.x; i < 66 * 128; i += 256) {
      int pc = i / 128, c = i % 128;
      float v = s[c * 66 + pc];
      unsigned short hb = f2bf(v);
      size_t o = obase + (size_t)pc * 256 + h * 128 + c;
      hi[o] = hb;
      lo[o] = f2bf(v - bf2f(hb));
    }
  }
}

// ---------------------------------------------------------------------------
// pack_w: OIHW fp32 -> [tap][co][ci] bf16 hi/lo
// ---------------------------------------------------------------------------
__global__ void pack_w(const float* __restrict__ w, unsigned short* __restrict__ hi,
                       unsigned short* __restrict__ lo, int COUT) {
  int i = blockIdx.x * 256 + threadIdx.x;
  int tot = COUT * 256 * 9;
  if (i >= tot) return;
  int co = i / (256 * 9);
  int r  = i - co * 256 * 9;
  int ci = r / 9;
  int k  = r - ci * 9;
  float v = w[i];
  unsigned short h = f2bf(v);
  size_t o = ((size_t)k * COUT + co) * 256 + ci;
  hi[o] = h;
  lo[o] = f2bf(v - bf2f(h));
}

// ---------------------------------------------------------------------------
// zero_border: zero the halo of a packed activation tensor pair
// ---------------------------------------------------------------------------
__global__ void zero_border(unsigned short* __restrict__ hi, unsigned short* __restrict__ lo) {
  int i = blockIdx.x * 256 + threadIdx.x;   // 32 * 260 * 256
  if (i >= 32 * 260 * 256) return;
  int c = i & 255;
  int p = i >> 8;
  int b = p / 260;
  int q = p - b * 260;
  int pr, pc;
  if (q < 66) { pr = 0; pc = q; }
  else if (q < 132) { pr = 65; pc = q - 66; }
  else { int u = q - 132; pr = 1 + (u >> 1); pc = (u & 1) * 65; }
  size_t o = ((size_t)(b * 66 + pr) * 66 + pc) * 256 + c;
  hi[o] = 0; lo[o] = 0;
}

// ---------------------------------------------------------------------------
// MFMA 3x3 conv + BN + ReLU.  Split-bf16 3-pass (hi*hi + lo*hi + hi*lo).
// Block: 128 px (2 rows x 64) x 128 cout.  256 threads = 4 waves.
//   - ALL staging via global_load_lds (16 B): zero staging VGPRs, no spills.
//   - A tile (264 px x 32ci, hi/lo) single LDS buffer, XOR-swizzled:
//     cell(p, hl, q) at p*128 + ((hl*4|q)^(p&7))*16.  DMA dest is linear in
//     lane order; the XOR permutation is applied to the per-lane SOURCE addr.
//   - B tile (128 co x 32ci, hi/lo) LDS double-buffer, same swizzle; slot
//     s+1 DMA'd while computing slot s; the per-slot barrier drains it.
//   - MFMA order identical to previous rounds (bitwise-same numerics).
//   - Epilogue transposes acc through LDS -> fully coalesced uint4 stores.
//   - Round-0 block mapping (no XCD swizzle): co-resident blocks share one
//     128-co weight half -> 2.36 MB, L2-resident per XCD.
// ---------------------------------------------------------------------------
#define ABUF_BYTES 33792           // 264 px * 128 B (= 2112 * 16)
#define BBASE      33792
#define BBUF_BYTES 16384           // 128 co * 128 B (= 1024 * 16)
#define SMEM_SZ    66560           // A + 2x B

template <int COUT, int OUTMODE>
__global__ __launch_bounds__(256, 2) void conv3x3_mfma(
    const unsigned short* __restrict__ Phi, const unsigned short* __restrict__ Plo,
    const unsigned short* __restrict__ Whi, const unsigned short* __restrict__ Wlo,
    const float* __restrict__ gam, const float* __restrict__ bet,
    unsigned short* __restrict__ Ohi, unsigned short* __restrict__ Olo,
    float* __restrict__ Ofp) {
  const int mb   = blockIdx.x % 1024;
  const int nblk = blockIdx.x / 1024;   // 0..COUT/128-1

  const int b     = mb >> 5;
  const int ypair = mb & 31;
  const int Y     = ypair * 2;          // padded input row base (= first out y)

  const int tid  = threadIdx.x;
  const int lane = tid & 63;
  const int wv   = tid >> 6;
  const int l15  = lane & 15;
  const int quad = lane >> 4;
  const int mhalf = (wv & 1) * 64;
  const int nbase = (wv >> 1) * 64;

  __shared__ __align__(16) char smem[SMEM_SZ];

  // per-mi pixel index base (p = pb + tap offset)
  int pb[4];
#pragma unroll
  for (int mi = 0; mi < 4; ++mi) {
    int px = mhalf + mi * 16 + l15;
    pb[mi] = (px >> 6) * 66 + (px & 63);
  }
  // B read offsets within a B buffer (fixed per thread)
  int boffs[4];
#pragma unroll
  for (int ni = 0; ni < 4; ++ni) {
    int col = nbase + ni * 16 + l15;                 // 0..127
    boffs[ni] = (col << 7) + (((quad ^ col) & 7) << 4);
  }

  f32x4 acc[4][4];
#pragma unroll
  for (int mi = 0; mi < 4; ++mi)
#pragma unroll
    for (int ni = 0; ni < 4; ++ni) acc[mi][ni] = (f32x4)0.f;

  const size_t ibase = ((size_t)(b * 66 + Y) * 66) * 256;  // shorts

  // ---- DMA staging (no registers) ----
  // B slot: 1024 uint4.  4 code-level DMAs; dest linear, source XOR-permuted.
  auto dmaB = [&](int tt, int cc, int bsel) {
#pragma unroll
    for (int k = 0; k < 4; ++k) {
      int idx = k * 256 + tid;
      int co = idx >> 3, s7 = idx & 7;
      int hq = s7 ^ (co & 7);
      const unsigned short* src = (hq & 4) ? Wlo : Whi;
      const unsigned short* g = src + (size_t)tt * (COUT * 256)
                                + ((size_t)(nblk * 128 + co)) * 256 + cc * 32 + (hq & 3) * 8;
      // wave-uniform LDS base; HW adds lane*16
      char* l = smem + BBASE + bsel * BBUF_BYTES + (k * 256 + wv * 64) * 16;
      gload16(g, l);
    }
  };
  // A chunk: 2112 uint4 (33 wave-instructions; j==8 is wave 0 only).
  auto dmaA = [&](int cc) {
#pragma unroll
    for (int j = 0; j < 9; ++j) {
      if (j * 4 + wv < 33) {
        int idx = j * 256 + tid;
        int p = idx >> 3, s7 = idx & 7;
        int hq = s7 ^ (p & 7);
        const unsigned short* src = (hq & 4) ? Plo : Phi;
        const unsigned short* g = src + ibase + (size_t)p * 256 + (hq & 3) * 8 + cc * 32;
        char* l = smem + (j * 256 + wv * 64) * 16;
        gload16(g, l);
      }
    }
  };

  // ---- prologue: DMA A chunk 0 and B slot 0 (buf 0); barrier drains ----
  dmaA(0);
  dmaB(0, 0, 0);
  __syncthreads();

  // ---- main loop: 8 chunks x 9 taps; B double-buffer parity compile-time --
  for (int c2 = 0; c2 < 8; c2 += 2) {
#pragma unroll
    for (int h = 0; h < 2; ++h) {
      const int c = c2 + h;
#pragma unroll
      for (int t = 0; t < 9; ++t) {
        const int par = (h + t) & 1;              // parity of slot (c*9+t)
        if (!(c == 7 && t == 8)) {
          int nt = (t == 8) ? 0 : t + 1;
          int nc = (t == 8) ? c + 1 : c;
          dmaB(nt, nc, par ^ 1);                  // next slot -> other buffer
        }
        const int dtap = (t / 3) * 66 + (t % 3);
        bf16x8 ah[4], al[4], bh[4], bl[4];
#pragma unroll
        for (int mi = 0; mi < 4; ++mi) {
          int p = pb[mi] + dtap;
          int a = (p << 7) + (((quad ^ p) & 7) << 4);
          ah[mi] = *(const bf16x8*)(smem + a);
          al[mi] = *(const bf16x8*)(smem + (a ^ 64));
        }
        const int bb = BBASE + par * BBUF_BYTES;
#pragma unroll
        for (int ni = 0; ni < 4; ++ni) {
          bh[ni] = *(const bf16x8*)(smem + bb + boffs[ni]);
          bl[ni] = *(const bf16x8*)(smem + bb + (boffs[ni] ^ 64));
        }
#pragma unroll
        for (int mi = 0; mi < 4; ++mi)
#pragma unroll
          for (int ni = 0; ni < 4; ++ni) {
            acc[mi][ni] = __builtin_amdgcn_mfma_f32_16x16x32_bf16(ah[mi], bh[ni], acc[mi][ni], 0, 0, 0);
            acc[mi][ni] = __builtin_amdgcn_mfma_f32_16x16x32_bf16(al[mi], bh[ni], acc[mi][ni], 0, 0, 0);
            acc[mi][ni] = __builtin_amdgcn_mfma_f32_16x16x32_bf16(ah[mi], bl[ni], acc[mi][ni], 0, 0, 0);
          }
        if (!(c == 7 && t == 8)) {
          __syncthreads();            // drains DMAs: B[s+1] ready; buf[par] free
          if (t == 8) {               // A[c] fully consumed -> refill in place
            dmaA(c + 1);
            __syncthreads();          // drain A[c+1] before chunk c+1 reads it
          }
        }
      }
    }
  }

  // ---- epilogue: BN + ReLU, transpose through LDS, coalesced stores ----
  __syncthreads();                    // all waves done with LDS tiles
  float scn[4], bin[4];
#pragma unroll
  for (int ni = 0; ni < 4; ++ni) {
    int co = nblk * 128 + nbase + ni * 16 + l15;
    scn[ni] = gam[co] * BN_SCALE;
    bin[ni] = bet[co];
  }

  float* SL = (float*)smem;                         // [64][129] f32 per pass
#pragma unroll
  for (int pass = 0; pass < 2; ++pass) {
    if ((wv & 1) == pass) {
#pragma unroll
      for (int mi = 0; mi < 4; ++mi)
#pragma unroll
        for (int ni = 0; ni < 4; ++ni)
#pragma unroll
          for (int r = 0; r < 4; ++r) {
            int lpx = mi * 16 + quad * 4 + r;       // 0..63 within this pass
            int co  = nbase + ni * 16 + l15;        // 0..127
            SL[lpx * 129 + co] = fmaxf(acc[mi][ni][r] * scn[ni] + bin[ni], 0.f);
          }
    }
    __syncthreads();
    if (OUTMODE == 0) {
#pragma unroll
      for (int it = 0; it < 4; ++it) {
        int u = it * 256 + tid;
        int lpx = u >> 4, oct = u & 15;
        const float* row = SL + lpx * 129 + oct * 8;
        __align__(16) unsigned short hs[8], ls[8];
#pragma unroll
        for (int j = 0; j < 8; ++j) {
          float v = row[j];
          unsigned short hb = f2bf(v);
          hs[j] = hb;
          ls[j] = f2bf(v - bf2f(hb));
        }
        size_t o = ((size_t)(b * 66 + Y + pass + 1) * 66 + lpx + 1) * 256 + nblk * 128 + oct * 8;
        *(uint4*)(Ohi + o) = *(const uint4*)hs;
        *(uint4*)(Olo + o) = *(const uint4*)ls;
      }
    } else {
#pragma unroll
      for (int it = 0; it < 4; ++it) {
        int u = it * 256 + tid;
        int coL = u >> 3, xo = u & 7;
        __align__(16) float vv[8];
#pragma unroll
        for (int j = 0; j < 8; ++j) vv[j] = SL[(xo * 8 + j) * 129 + coL];
        size_t o = ((size_t)(b * COUT + nblk * 128 + coL)) * 4096 + (size_t)(Y + pass) * 64 + xo * 8;
        *(uint4*)(Ofp + o)     = *(const uint4*)&vv[0];
        *(uint4*)(Ofp + o + 4) = *(const uint4*)&vv[4];
      }
    }
    __syncthreads();
  }
}

// ---------------------------------------------------------------------------
// 1x1 conv + bias (+ optional softplus). One thread per pixel, CO accs.
// ---------------------------------------------------------------------------
template <int CO, int CIN>
__global__ __launch_bounds__(256) void conv1x1_kernel(
    const float* __restrict__ in, const float* __restrict__ w,
    const float* __restrict__ bias, float* __restrict__ out, int do_softplus) {
  __shared__ float s_w[CO * CIN];
  const int b   = blockIdx.x >> 4;
  const int pix = ((blockIdx.x & 15) << 8) + threadIdx.x;
  for (int i = threadIdx.x; i < CO * CIN; i += 256) s_w[i] = w[i];
  __syncthreads();

  float acc[CO];
#pragma unroll
  for (int co = 0; co < CO; ++co) acc[co] = 0.f;

  const float* ip = in + (size_t)b * CIN * HW_ + pix;
  for (int ci = 0; ci < CIN; ++ci) {
    float v = ip[(size_t)ci * HW_];
#pragma unroll
    for (int co = 0; co < CO; ++co) acc[co] = fmaf(v, s_w[co * CIN + ci], acc[co]);
  }
  float* op = out + (size_t)b * CO * HW_ + pix;
#pragma unroll
  for (int co = 0; co < CO; ++co) {
    float x = acc[co] + bias[co];
    if (do_softplus) x = fmaxf(x, 0.f) + log1pf(expf(-fabsf(x)));
    op[(size_t)co * HW_] = x;
  }
}

// ---------------------------------------------------------------------------
// soft-argmax over each (b,k) 64x64 heatmap
// ---------------------------------------------------------------------------
__global__ __launch_bounds__(256) void soft_argmax_kernel(
    const float* __restrict__ heat, float* __restrict__ cg,
    float* __restrict__ scores) {
  const int bk = blockIdx.x;
  const float* h = heat + (size_t)bk * HW_;
  const int tid = threadIdx.x;
  __shared__ float sred[256];

  float v[16];
  float lmax = -INFINITY;
#pragma unroll
  for (int i = 0; i < 16; ++i) {
    v[i] = h[tid + (i << 8)];
    lmax = fmaxf(lmax, v[i]);
  }
  sred[tid] = lmax; __syncthreads();
  for (int s = 128; s > 0; s >>= 1) {
    if (tid < s) sred[tid] = fmaxf(sred[tid], sred[tid + s]);
    __syncthreads();
  }
  const float m = sred[0];
  __syncthreads();

  float s = 0.f, sx = 0.f, sy = 0.f;
#pragma unroll
  for (int i = 0; i < 16; ++i) {
    int idx = tid + (i << 8);
    float e = expf(v[i] - m);
    s += e;
    sx += e * (float)(idx & 63);
    sy += e * (float)(idx >> 6);
  }
  sred[tid] = s; __syncthreads();
  for (int st = 128; st > 0; st >>= 1) { if (tid < st) sred[tid] += sred[tid + st]; __syncthreads(); }
  const float S = sred[0]; __syncthreads();
  sred[tid] = sx; __syncthreads();
  for (int st = 128; st > 0; st >>= 1) { if (tid < st) sred[tid] += sred[tid + st]; __syncthreads(); }
  const float SX = sred[0]; __syncthreads();
  sred[tid] = sy; __syncthreads();
  for (int st = 128; st > 0; st >>= 1) { if (tid < st) sred[tid] += sred[tid + st]; __syncthreads(); }
  const float SY = sred[0];

  if (tid == 0) {
    cg[bk * 2]     = SX / S;
    cg[bk * 2 + 1] = SY / S;
    scores[bk]     = m;
  }
}

// ---------------------------------------------------------------------------
// local refine + blend + bilinear offset sampling + final coords; writes fw.
// ---------------------------------------------------------------------------
__global__ void refine_kernel(
    const float* __restrict__ heat, const float* __restrict__ off,
    const float* __restrict__ cg, const float* __restrict__ alpha_p,
    const float* __restrict__ fusion_p, float* __restrict__ coords_out,
    float* __restrict__ fw_out) {
  const int kp = blockIdx.x * 64 + threadIdx.x;
  const float fw = 1.f / (1.f + expf(-fusion_p[0]));
  if (kp == 0) fw_out[0] = fw;
  if (kp >= B_ * K_) return;

  const float a = 1.f / (1.f + expf(-alpha_p[0]));
  const float* h = heat + (size_t)kp * HW_;
  const float cgx = cg[kp * 2];
  const float cgy = cg[kp * 2 + 1];
  const int px = (int)rintf(fminf(fmaxf(cgx, 0.f), 63.f));
  const int py = (int)rintf(fminf(fmaxf(cgy, 0.f), 63.f));

  float vals[25];
  float m = -INFINITY;
#pragma unroll
  for (int dy = 0; dy < 5; ++dy) {
    int ya = py + dy - 2;
    int yc = min(max(ya, 0), 63);
#pragma unroll
    for (int dx = 0; dx < 5; ++dx) {
      int xa = px + dx - 2;
      int xc = min(max(xa, 0), 63);
      bool inb = (ya >= 0) && (ya < H_) && (xa >= 0) && (xa < W_);
      float val = inb ? h[yc * W_ + xc] : -INFINITY;
      vals[dy * 5 + dx] = val;
      m = fmaxf(m, val);
    }
  }
  float s = 0.f, rx = 0.f, ry = 0.f;
#pragma unroll
  for (int dy = 0; dy < 5; ++dy) {
    int ya = py + dy - 2;
    int yc = min(max(ya, 0), 63);
#pragma unroll
    for (int dx = 0; dx < 5; ++dx) {
      int xa = px + dx - 2;
      int xc = min(max(xa, 0), 63);
      float e = expf(vals[dy * 5 + dx] - m);
      s += e;
      rx += e * (float)xc;
      ry += e * (float)yc;
    }
  }
  rx /= s; ry /= s;

  float cx = a * cgx + (1.f - a) * rx;
  float cy = a * cgy + (1.f - a) * ry;

  const float ix = fminf(fmaxf(cx, 0.f), 63.f);
  const float iy = fminf(fmaxf(cy, 0.f), 63.f);
  const float x0 = floorf(ix), y0 = floorf(iy);
  const float wx = ix - x0, wy = iy - y0;
  const int x0i = min(max((int)x0, 0), 63);
  const int x1i = min(x0i + 1, 63);
  const int y0i = min(max((int)y0, 0), 63);
  const int y1i = min(y0i + 1, 63);

  float smp[2];
#pragma unroll
  for (int ch = 0; ch < 2; ++ch) {
    const float* oc = off + ((size_t)kp * 2 + ch) * HW_;
    float v00 = oc[y0i * W_ + x0i];
    float v01 = oc[y0i * W_ + x1i];
    float v10 = oc[y1i * W_ + x0i];
    float v11 = oc[y1i * W_ + x1i];
    smp[ch] = (1.f - wy) * ((1.f - wx) * v00 + wx * v01)
            + wy * ((1.f - wx) * v10 + wx * v11);
  }
  cx += fw * smp[0];
  cy += fw * smp[1];
  coords_out[kp * 2]     = cx;
  coords_out[kp * 2 + 1] = cy;
}

// ---------------------------------------------------------------------------
extern "C" void kernel_launch(void* const* d_in, const int* in_sizes, int n_in,
                              void* d_out, int out_size, void* d_ws, size_t ws_size,
                              hipStream_t stream) {
  const float* x    = (const float*)d_in[0];
  const float* w_s1 = (const float*)d_in[1];
  const float* g_s1 = (const float*)d_in[2];
  const float* b_s1 = (const float*)d_in[3];
  const float* w_s2 = (const float*)d_in[4];
  const float* g_s2 = (const float*)d_in[5];
  const float* b_s2 = (const float*)d_in[6];
  const float* w_h1 = (const float*)d_in[7];
  const float* g_h1 = (const float*)d_in[8];
  const float* b_h1 = (const float*)d_in[9];
  const float* w_h2 = (const float*)d_in[10];
  const float* c_h2 = (const float*)d_in[11];
  const float* w_o1 = (const float*)d_in[12];
  const float* g_o1 = (const float*)d_in[13];
  const float* b_o1 = (const float*)d_in[14];
  const float* w_o2 = (const float*)d_in[15];
  const float* c_o2 = (const float*)d_in[16];
  const float* w_v1 = (const float*)d_in[17];
  const float* g_v1 = (const float*)d_in[18];
  const float* b_v1 = (const float*)d_in[19];
  const float* w_v2 = (const float*)d_in[20];
  const float* c_v2 = (const float*)d_in[21];
  const float* alpha  = (const float*)d_in[22];
  const float* fusion = (const float*)d_in[23];

  float* out = (float*)d_out;
  char*  ws  = (char*)d_ws;

  unsigned short* xp_hi = (unsigned short*)(ws + XP_HI);
  unsigned short* xp_lo = (unsigned short*)(ws + XP_LO);
  unsigned short* s1_hi = (unsigned short*)(ws + S1_HI);
  unsigned short* s1_lo = (unsigned short*)(ws + S1_LO);
  unsigned short* s2_hi = (unsigned short*)(ws + S2_HI);
  unsigned short* s2_lo = (unsigned short*)(ws + S2_LO);
  unsigned short* ws1_hi = (unsigned short*)(ws + WS1_HI);
  unsigned short* ws1_lo = (unsigned short*)(ws + WS1_LO);
  unsigned short* ws2_hi = (unsigned short*)(ws + WS2_HI);
  unsigned short* ws2_lo = (unsigned short*)(ws + WS2_LO);
  unsigned short* wh1_hi = (unsigned short*)(ws + WH1_HI);
  unsigned short* wh1_lo = (unsigned short*)(ws + WH1_LO);
  unsigned short* wo1_hi = (unsigned short*)(ws + WO1_HI);
  unsigned short* wo1_lo = (unsigned short*)(ws + WO1_LO);
  unsigned short* wv1_hi = (unsigned short*)(ws + WV1_HI);
  unsigned short* wv1_lo = (unsigned short*)(ws + WV1_LO);
  float* F0  = (float*)(ws + 0);             // reuses XP region for h1/o1/v1 fp32
  float* cgb = (float*)(ws + CG_OFF);

  dim3 blk(256);

  // ---- pack inputs & weights, zero halos ----
  pack_x<<<32 * 66, blk, 0, stream>>>(x, xp_hi, xp_lo);
  pack_w<<<256 * 9, blk, 0, stream>>>(w_s1, ws1_hi, ws1_lo, 256);
  pack_w<<<256 * 9, blk, 0, stream>>>(w_s2, ws2_hi, ws2_lo, 256);
  pack_w<<<256 * 9, blk, 0, stream>>>(w_h1, wh1_hi, wh1_lo, 256);
  pack_w<<<256 * 9, blk, 0, stream>>>(w_o1, wo1_hi, wo1_lo, 256);
  pack_w<<<128 * 9, blk, 0, stream>>>(w_v1, wv1_hi, wv1_lo, 128);
  zero_border<<<8320, blk, 0, stream>>>(s1_hi, s1_lo);
  zero_border<<<8320, blk, 0, stream>>>(s2_hi, s2_lo);

  // ---- backbone convs (MFMA) ----
  conv3x3_mfma<256, 0><<<2048, blk, 0, stream>>>(xp_hi, xp_lo, ws1_hi, ws1_lo,
                                                 g_s1, b_s1, s1_hi, s1_lo, nullptr);
  conv3x3_mfma<256, 0><<<2048, blk, 0, stream>>>(s1_hi, s1_lo, ws2_hi, ws2_lo,
                                                 g_s2, b_s2, s2_hi, s2_lo, nullptr);
  conv3x3_mfma<256, 1><<<2048, blk, 0, stream>>>(s2_hi, s2_lo, wh1_hi, wh1_lo,
                                                 g_h1, b_h1, nullptr, nullptr, F0);
  conv1x1_kernel<17, 256><<<512, blk, 0, stream>>>(F0, w_h2, c_h2, out + HEAT_OFF, 0);
  conv3x3_mfma<256, 1><<<2048, blk, 0, stream>>>(s2_hi, s2_lo, wo1_hi, wo1_lo,
                                                 g_o1, b_o1, nullptr, nullptr, F0);
  conv1x1_kernel<34, 256><<<512, blk, 0, stream>>>(F0, w_o2, c_o2, out + OFF_OFF, 0);
  conv3x3_mfma<128, 1><<<1024, blk, 0, stream>>>(s2_hi, s2_lo, wv1_hi, wv1_lo,
                                                 g_v1, b_v1, nullptr, nullptr, F0);
  conv1x1_kernel<17, 128><<<512, blk, 0, stream>>>(F0, w_v2, c_v2, out + VAR_OFF, 1);

  // ---- heads ----
  soft_argmax_kernel<<<544, blk, 0, stream>>>(out + HEAT_OFF, cgb, out + SCORE_OFF);
  refine_kernel<<<9, dim3(64), 0, stream>>>(out + HEAT_OFF, out + OFF_OFF, cgb,
                                            alpha, fusion,
                                            out + COORD_OFF, out + FW_OFF);
}